// Round 1
// baseline (505.505 us; speedup 1.0000x reference)
//
#include <hip/hip_runtime.h>

typedef unsigned short u16;
typedef unsigned int u32;
typedef __attribute__((ext_vector_type(8))) short bf16x8;   // 8 bf16 in 4 VGPRs
typedef __attribute__((ext_vector_type(4))) float f32x4;
typedef __attribute__((ext_vector_type(4))) u16 u16x4;

typedef __attribute__((address_space(1))) unsigned int as1_u32;
typedef __attribute__((address_space(3))) unsigned int as3_u32;

#define SEQ 4096
#define HID 1024
#define NHEAD 16
#define BATCH 2

__device__ __forceinline__ u16 f2b(float f) {
  union { float f; u32 u; } v; v.f = f;
  u32 r = v.u + 0x7FFFu + ((v.u >> 16) & 1u);   // RNE
  return (u16)(r >> 16);
}

__device__ __forceinline__ void async_cp16(const void* g, void* l) {
  __builtin_amdgcn_global_load_lds((const as1_u32*)g, (as3_u32*)l, 16, 0, 0);
}

// ---------------- fp32 -> bf16 converts ----------------
__global__ __launch_bounds__(256) void cvt_qkv(
    const float* __restrict__ a, const float* __restrict__ b, const float* __restrict__ c,
    u16* __restrict__ oa, u16* __restrict__ ob, u16* __restrict__ oc) {
  const int total = 3 << 21;          // 3 tensors x 2^21 float4
  for (int i = blockIdx.x * blockDim.x + threadIdx.x; i < total; i += gridDim.x * blockDim.x) {
    const int sel = i >> 21;
    const int j = i & ((1 << 21) - 1);
    const float* src = sel == 0 ? a : (sel == 1 ? b : c);
    u16* dst = sel == 0 ? oa : (sel == 1 ? ob : oc);
    float4 f = ((const float4*)src)[j];
    u16x4 o; o.x = f2b(f.x); o.y = f2b(f.y); o.z = f2b(f.z); o.w = f2b(f.w);
    ((u16x4*)dst)[j] = o;
  }
}

__global__ __launch_bounds__(256) void cvt_w(
    const float* __restrict__ a, const float* __restrict__ b,
    const float* __restrict__ c, const float* __restrict__ d,
    u16* __restrict__ oa, u16* __restrict__ ob, u16* __restrict__ oc, u16* __restrict__ od) {
  const int total = 4 << 18;          // 4 weights x 2^18 float4
  for (int i = blockIdx.x * blockDim.x + threadIdx.x; i < total; i += gridDim.x * blockDim.x) {
    const int sel = i >> 18;
    const int j = i & ((1 << 18) - 1);
    const float* src = sel == 0 ? a : (sel == 1 ? b : (sel == 2 ? c : d));
    u16* dst = sel == 0 ? oa : (sel == 1 ? ob : (sel == 2 ? oc : od));
    float4 f = ((const float4*)src)[j];
    u16x4 o; o.x = f2b(f.x); o.y = f2b(f.y); o.z = f2b(f.z); o.w = f2b(f.w);
    ((u16x4*)dst)[j] = o;
  }
}

// ---------------- GEMM: C = A[MxK] * Bw[NxK]^T + bias ----------------
// MODE 0: bf16 row-major out. MODE 1: fp32 row-major out.
// MODE 2: bf16 transposed out -> vT[(b*16+h)*64+d][token]  (N==HID, rows%4096 layout)
template <int MODE>
__global__ __launch_bounds__(256, 2) void gemm_bt(
    const u16* __restrict__ A, const u16* __restrict__ Bw,
    const float* __restrict__ bias, void* __restrict__ Cout,
    int M, int N, int K) {
  __shared__ __align__(16) u16 As[128 * 32];
  __shared__ __align__(16) u16 Bs[128 * 32];

  const int tid = threadIdx.x;
  const int lane = tid & 63;
  const int wave = tid >> 6;
  const int l15 = lane & 15;
  const int quad = lane >> 4;
  const int wr = wave >> 1;
  const int wc = wave & 1;
  const long brow = (long)blockIdx.y * 128;
  const long bcol = (long)blockIdx.x * 128;

  // staging: 8 chunks of 1024B per matrix; wave w owns chunks w and w+4.
  const int srow = lane >> 2;          // row within 16-row chunk
  const int scol = (lane & 3) * 8;     // bf16 elems (16B)
  const u16* Ag0 = A + (brow + wave * 16 + srow) * (long)K + scol;
  const u16* Ag1 = A + (brow + (wave + 4) * 16 + srow) * (long)K + scol;
  const u16* Bg0 = Bw + (bcol + wave * 16 + srow) * (long)K + scol;
  const u16* Bg1 = Bw + (bcol + (wave + 4) * 16 + srow) * (long)K + scol;
  u16* Al0 = As + wave * 512;          // wave-uniform LDS bases (HW adds lane*16B)
  u16* Al1 = As + (wave + 4) * 512;
  u16* Bl0 = Bs + wave * 512;
  u16* Bl1 = Bs + (wave + 4) * 512;

  f32x4 acc[4][4];
#pragma unroll
  for (int i = 0; i < 4; ++i)
#pragma unroll
    for (int j = 0; j < 4; ++j) acc[i][j] = f32x4{0.f, 0.f, 0.f, 0.f};

  const u16* Afb = As + (wr * 64 + l15) * 32 + quad * 8;
  const u16* Bfb = Bs + (wc * 64 + l15) * 32 + quad * 8;

  for (int k0 = 0; k0 < K; k0 += 32) {
    async_cp16(Ag0 + k0, Al0);
    async_cp16(Ag1 + k0, Al1);
    async_cp16(Bg0 + k0, Bl0);
    async_cp16(Bg1 + k0, Bl1);
    __syncthreads();                       // drains vmcnt -> staging visible
    bf16x8 af[4], bfv[4];
#pragma unroll
    for (int mt = 0; mt < 4; ++mt) af[mt] = *(const bf16x8*)(Afb + mt * 512);
#pragma unroll
    for (int nt = 0; nt < 4; ++nt) bfv[nt] = *(const bf16x8*)(Bfb + nt * 512);
#pragma unroll
    for (int mt = 0; mt < 4; ++mt)
#pragma unroll
      for (int nt = 0; nt < 4; ++nt)
        acc[mt][nt] = __builtin_amdgcn_mfma_f32_16x16x32_bf16(af[mt], bfv[nt], acc[mt][nt], 0, 0, 0);
    __syncthreads();                       // protect LDS before next stage
  }

  const long crow0 = brow + wr * 64;
  const long ccol0 = bcol + wc * 64;
#pragma unroll
  for (int nt = 0; nt < 4; ++nt) {
    const long col = ccol0 + nt * 16 + l15;
    const float bv = bias[col];
    if (MODE == 2) {
#pragma unroll
      for (int mt = 0; mt < 4; ++mt) {
        const long tokbase = crow0 + mt * 16 + quad * 4;  // 4 consecutive tokens
        const long b = tokbase >> 12;
        const long tok = tokbase & 4095;
        const long h = col >> 6, d = col & 63;
        u16x4 pk;
        pk.x = f2b(acc[mt][nt][0] + bv);
        pk.y = f2b(acc[mt][nt][1] + bv);
        pk.z = f2b(acc[mt][nt][2] + bv);
        pk.w = f2b(acc[mt][nt][3] + bv);
        *(u16x4*)((u16*)Cout + ((b * 16 + h) * 64 + d) * (long)SEQ + tok) = pk;
      }
    } else {
#pragma unroll
      for (int mt = 0; mt < 4; ++mt)
#pragma unroll
        for (int r = 0; r < 4; ++r) {
          const long row = crow0 + mt * 16 + quad * 4 + r;
          const float v = acc[mt][nt][r] + bv;
          if (MODE == 1) ((float*)Cout)[row * (long)N + col] = v;
          else           ((u16*)Cout)[row * (long)N + col] = f2b(v);
        }
    }
  }
}

// ---------------- windowed attention ----------------
// block = (b, window). 4 waves x 4 heads each. Writes attended (bf16 [B*S][HID])
// and the diagonal 64x64 block of the head-mean attention map.
__global__ __launch_bounds__(256, 1) void attn_win(
    const u16* __restrict__ qp, const u16* __restrict__ kp,
    const u16* __restrict__ vT, u16* __restrict__ attended,
    float* __restrict__ attn) {
  __shared__ float accum[64][66];                  // head-sum of P
  __shared__ __align__(16) u16 Plds[4][64][72];    // per-wave P (bf16), pitch 144B

  const int tid = threadIdx.x;
  const int lane = tid & 63;
  const int wave = tid >> 6;
  const int l15 = lane & 15;
  const int quad = lane >> 4;
  const int b = blockIdx.x >> 6;
  const int n = blockIdx.x & 63;
  const long row0 = (long)b * SEQ + (long)n * 64;

  for (int i = tid; i < 64 * 66; i += 256) (&accum[0][0])[i] = 0.f;
  __syncthreads();

  u16(*Pw)[72] = Plds[wave];

  for (int hi = 0; hi < 4; ++hi) {
    const int h = wave + hi * 4;
    const long cbase = (long)h * 64;

    // --- S = Q K^T * scale ---
    f32x4 s[4][4];
#pragma unroll
    for (int i = 0; i < 4; ++i)
#pragma unroll
      for (int j = 0; j < 4; ++j) s[i][j] = f32x4{0.f, 0.f, 0.f, 0.f};
#pragma unroll
    for (int kt = 0; kt < 2; ++kt) {
      bf16x8 aq[4], bkf[4];
#pragma unroll
      for (int mt = 0; mt < 4; ++mt)
        aq[mt] = *(const bf16x8*)(qp + (row0 + mt * 16 + l15) * HID + cbase + kt * 32 + quad * 8);
#pragma unroll
      for (int nt = 0; nt < 4; ++nt)
        bkf[nt] = *(const bf16x8*)(kp + (row0 + nt * 16 + l15) * HID + cbase + kt * 32 + quad * 8);
#pragma unroll
      for (int mt = 0; mt < 4; ++mt)
#pragma unroll
        for (int nt = 0; nt < 4; ++nt)
          s[mt][nt] = __builtin_amdgcn_mfma_f32_16x16x32_bf16(aq[mt], bkf[nt], s[mt][nt], 0, 0, 0);
    }

    // --- softmax over the 64 keys (cols live across 16 lanes x 4 nt) ---
#pragma unroll
    for (int mt = 0; mt < 4; ++mt) {
#pragma unroll
      for (int r = 0; r < 4; ++r) {
        float m = -1e30f;
#pragma unroll
        for (int nt = 0; nt < 4; ++nt) { s[mt][nt][r] *= 0.125f; m = fmaxf(m, s[mt][nt][r]); }
        m = fmaxf(m, __shfl_xor(m, 1));
        m = fmaxf(m, __shfl_xor(m, 2));
        m = fmaxf(m, __shfl_xor(m, 4));
        m = fmaxf(m, __shfl_xor(m, 8));
        float sum = 0.f;
#pragma unroll
        for (int nt = 0; nt < 4; ++nt) { float e = __expf(s[mt][nt][r] - m); s[mt][nt][r] = e; sum += e; }
        sum += __shfl_xor(sum, 1);
        sum += __shfl_xor(sum, 2);
        sum += __shfl_xor(sum, 4);
        sum += __shfl_xor(sum, 8);
        const float inv = 1.f / sum;
#pragma unroll
        for (int nt = 0; nt < 4; ++nt) s[mt][nt][r] *= inv;
      }
    }

    // --- accumulate head-mean + stash P for layout transform ---
#pragma unroll
    for (int mt = 0; mt < 4; ++mt)
#pragma unroll
      for (int nt = 0; nt < 4; ++nt)
#pragma unroll
        for (int r = 0; r < 4; ++r) {
          const float p = s[mt][nt][r];
          atomicAdd(&accum[mt * 16 + quad * 4 + r][nt * 16 + l15], p);
          Pw[mt * 16 + quad * 4 + r][nt * 16 + l15] = f2b(p);
        }

    // --- O = P V ---
    f32x4 o[4][4];
#pragma unroll
    for (int i = 0; i < 4; ++i)
#pragma unroll
      for (int j = 0; j < 4; ++j) o[i][j] = f32x4{0.f, 0.f, 0.f, 0.f};
    const long vbase = ((long)(b * 16 + h) * 64) * SEQ;
#pragma unroll
    for (int kt = 0; kt < 2; ++kt) {
      bf16x8 ap[4], bvf[4];
#pragma unroll
      for (int mt = 0; mt < 4; ++mt)
        ap[mt] = *(const bf16x8*)(&Pw[mt * 16 + l15][kt * 32 + quad * 8]);
#pragma unroll
      for (int nt = 0; nt < 4; ++nt)
        bvf[nt] = *(const bf16x8*)(vT + vbase + (long)(nt * 16 + l15) * SEQ + n * 64 + kt * 32 + quad * 8);
#pragma unroll
      for (int mt = 0; mt < 4; ++mt)
#pragma unroll
        for (int nt = 0; nt < 4; ++nt)
          o[mt][nt] = __builtin_amdgcn_mfma_f32_16x16x32_bf16(ap[mt], bvf[nt], o[mt][nt], 0, 0, 0);
    }

    // --- store attended bf16 [token][h*64+d] ---
#pragma unroll
    for (int mt = 0; mt < 4; ++mt)
#pragma unroll
      for (int nt = 0; nt < 4; ++nt)
#pragma unroll
        for (int r = 0; r < 4; ++r)
          attended[(row0 + mt * 16 + quad * 4 + r) * HID + cbase + nt * 16 + l15] = f2b(o[mt][nt][r]);
  }

  __syncthreads();
  const float inv16 = 1.f / 16.f;
  float* obase = attn + (long)b * SEQ * SEQ + (long)n * 64 * SEQ + (long)n * 64;
  for (int i = tid; i < 64 * 64; i += 256) {
    const int r = i >> 6, c = i & 63;
    obase[(long)r * SEQ + c] = accum[r][c] * inv16;
  }
}

extern "C" void kernel_launch(void* const* d_in, const int* in_sizes, int n_in,
                              void* d_out, int out_size, void* d_ws, size_t ws_size,
                              hipStream_t stream) {
  (void)in_sizes; (void)n_in; (void)out_size; (void)ws_size;
  const float* query = (const float*)d_in[0];
  const float* key   = (const float*)d_in[1];
  const float* value = (const float*)d_in[2];
  const float* Wq = (const float*)d_in[3];
  const float* bq = (const float*)d_in[4];
  const float* Wk = (const float*)d_in[5];
  const float* bk = (const float*)d_in[6];
  const float* Wv = (const float*)d_in[7];
  const float* bv = (const float*)d_in[8];
  const float* Wo = (const float*)d_in[9];
  const float* bo = (const float*)d_in[10];

  float* out  = (float*)d_out;
  float* attn = out + (size_t)BATCH * SEQ * HID;   // +8388608 floats

  char* ws = (char*)d_ws;
  const size_t MB = (size_t)1 << 20;
  u16* xq = (u16*)(ws + 0 * MB);    // later reused as 'attended'
  u16* xk = (u16*)(ws + 16 * MB);   // later reused as vT
  u16* xv = (u16*)(ws + 32 * MB);
  u16* wq = (u16*)(ws + 48 * MB);
  u16* wk = (u16*)(ws + 50 * MB);
  u16* wv = (u16*)(ws + 52 * MB);
  u16* wo = (u16*)(ws + 54 * MB);
  u16* qp = (u16*)(ws + 56 * MB);
  u16* kp = (u16*)(ws + 72 * MB);
  u16* vT  = xk;   // dead after K-projection
  u16* att = xq;   // dead after Q-projection

  // zero the (block-diagonal) attention map; diag blocks overwritten by attn_win
  hipMemsetAsync(attn, 0, (size_t)BATCH * SEQ * SEQ * sizeof(float), stream);

  cvt_qkv<<<2048, 256, 0, stream>>>(query, key, value, xq, xk, xv);
  cvt_w<<<512, 256, 0, stream>>>(Wq, Wk, Wv, Wo, wq, wk, wv, wo);

  dim3 gg(HID / 128, (BATCH * SEQ) / 128);  // (8, 64)
  gemm_bt<0><<<gg, 256, 0, stream>>>(xq, wq, bq, qp, BATCH * SEQ, HID, HID);
  gemm_bt<0><<<gg, 256, 0, stream>>>(xk, wk, bk, kp, BATCH * SEQ, HID, HID);
  gemm_bt<2><<<gg, 256, 0, stream>>>(xv, wv, bv, vT, BATCH * SEQ, HID, HID);

  attn_win<<<BATCH * 64, 256, 0, stream>>>(qp, kp, vT, att, attn);

  gemm_bt<1><<<gg, 256, 0, stream>>>(att, wo, bo, out, BATCH * SEQ, HID, HID);
}

// Round 2
// 416.666 us; speedup vs baseline: 1.2132x; 1.2132x over previous
//
#include <hip/hip_runtime.h>

typedef unsigned short u16;
typedef unsigned int u32;
typedef __attribute__((ext_vector_type(8))) short bf16x8;   // 8 bf16 in 4 VGPRs
typedef __attribute__((ext_vector_type(4))) float f32x4;
typedef __attribute__((ext_vector_type(4))) u16 u16x4;

typedef __attribute__((address_space(1))) unsigned int as1_u32;
typedef __attribute__((address_space(3))) unsigned int as3_u32;

#define SEQ 4096
#define HID 1024
#define NHEAD 16
#define BATCH 2

__device__ __forceinline__ u16 f2b(float f) {
  union { float f; u32 u; } v; v.f = f;
  u32 r = v.u + 0x7FFFu + ((v.u >> 16) & 1u);   // RNE
  return (u16)(r >> 16);
}

__device__ __forceinline__ float b2f(u16 b) {
  union { u32 u; float f; } v; v.u = ((u32)b) << 16;
  return v.f;
}

__device__ __forceinline__ void async_cp16(const void* g, void* l) {
  __builtin_amdgcn_global_load_lds((const as1_u32*)g, (as3_u32*)l, 16, 0, 0);
}

// ---------------- fp32 -> bf16 convert (all 7 tensors, one launch) ----------------
__global__ __launch_bounds__(256) void cvt_all(
    const float* __restrict__ q, const float* __restrict__ k, const float* __restrict__ v,
    const float* __restrict__ Wq, const float* __restrict__ Wk,
    const float* __restrict__ Wv, const float* __restrict__ Wo,
    u16* __restrict__ xq, u16* __restrict__ xk, u16* __restrict__ xv,
    u16* __restrict__ wq, u16* __restrict__ wk, u16* __restrict__ wv, u16* __restrict__ wo) {
  const int total = (3 << 21) + (4 << 18);   // 7,340,032 float4 groups
  for (int i = blockIdx.x * blockDim.x + threadIdx.x; i < total; i += gridDim.x * blockDim.x) {
    const float* src; u16* dst; int j;
    if (i < (3 << 21)) {
      const int sel = i >> 21; j = i & ((1 << 21) - 1);
      src = sel == 0 ? q : (sel == 1 ? k : v);
      dst = sel == 0 ? xq : (sel == 1 ? xk : xv);
    } else {
      const int ii = i - (3 << 21);
      const int sel = ii >> 18; j = ii & ((1 << 18) - 1);
      src = sel == 0 ? Wq : (sel == 1 ? Wk : (sel == 2 ? Wv : Wo));
      dst = sel == 0 ? wq : (sel == 1 ? wk : (sel == 2 ? wv : wo));
    }
    float4 f = ((const float4*)src)[j];
    u16x4 o; o.x = f2b(f.x); o.y = f2b(f.y); o.z = f2b(f.z); o.w = f2b(f.w);
    ((u16x4*)dst)[j] = o;
  }
}

// ---------------- GEMM: C = A[8192x1024] * Bw[1024x1024]^T + bias ----------------
// mode 0: bf16 row-major out. mode 1: fp32 row-major out.
// mode 2: bf16 transposed out -> vT[(b*16+h)*64+d][token]
struct Gemm3Args {
  const u16* A[3]; const u16* W[3]; const float* bias[3]; void* C[3]; int mode[3];
};

__global__ __launch_bounds__(256, 2) void gemm_bt_fused(Gemm3Args ga) {
  __shared__ __align__(16) u16 As[128 * 32];
  __shared__ __align__(16) u16 Bs[128 * 32];

  const int z = blockIdx.z;
  const u16* __restrict__ A  = ga.A[z];
  const u16* __restrict__ Bw = ga.W[z];
  const float* __restrict__ bias = ga.bias[z];
  void* __restrict__ Cout = ga.C[z];
  const int mode = ga.mode[z];
  const int K = HID, N = HID;

  const int tid = threadIdx.x;
  const int lane = tid & 63;
  const int wave = tid >> 6;
  const int l15 = lane & 15;
  const int quad = lane >> 4;
  const int wr = wave >> 1;
  const int wc = wave & 1;
  const long brow = (long)blockIdx.y * 128;
  const long bcol = (long)blockIdx.x * 128;

  const int srow = lane >> 2;          // row within 16-row chunk
  const int scol = (lane & 3) * 8;     // bf16 elems (16B)
  const u16* Ag0 = A + (brow + wave * 16 + srow) * (long)K + scol;
  const u16* Ag1 = A + (brow + (wave + 4) * 16 + srow) * (long)K + scol;
  const u16* Bg0 = Bw + (bcol + wave * 16 + srow) * (long)K + scol;
  const u16* Bg1 = Bw + (bcol + (wave + 4) * 16 + srow) * (long)K + scol;
  u16* Al0 = As + wave * 512;          // wave-uniform LDS bases (HW adds lane*16B)
  u16* Al1 = As + (wave + 4) * 512;
  u16* Bl0 = Bs + wave * 512;
  u16* Bl1 = Bs + (wave + 4) * 512;

  f32x4 acc[4][4];
#pragma unroll
  for (int i = 0; i < 4; ++i)
#pragma unroll
    for (int j = 0; j < 4; ++j) acc[i][j] = f32x4{0.f, 0.f, 0.f, 0.f};

  const u16* Afb = As + (wr * 64 + l15) * 32 + quad * 8;
  const u16* Bfb = Bs + (wc * 64 + l15) * 32 + quad * 8;

  for (int k0 = 0; k0 < K; k0 += 32) {
    async_cp16(Ag0 + k0, Al0);
    async_cp16(Ag1 + k0, Al1);
    async_cp16(Bg0 + k0, Bl0);
    async_cp16(Bg1 + k0, Bl1);
    __syncthreads();
    bf16x8 af[4], bfv[4];
#pragma unroll
    for (int mt = 0; mt < 4; ++mt) af[mt] = *(const bf16x8*)(Afb + mt * 512);
#pragma unroll
    for (int nt = 0; nt < 4; ++nt) bfv[nt] = *(const bf16x8*)(Bfb + nt * 512);
#pragma unroll
    for (int mt = 0; mt < 4; ++mt)
#pragma unroll
      for (int nt = 0; nt < 4; ++nt)
        acc[mt][nt] = __builtin_amdgcn_mfma_f32_16x16x32_bf16(af[mt], bfv[nt], acc[mt][nt], 0, 0, 0);
    __syncthreads();
  }

  const long crow0 = brow + wr * 64;
  const long ccol0 = bcol + wc * 64;
#pragma unroll
  for (int nt = 0; nt < 4; ++nt) {
    const long col = ccol0 + nt * 16 + l15;
    const float bv = bias[col];
    if (mode == 2) {
#pragma unroll
      for (int mt = 0; mt < 4; ++mt) {
        const long tokbase = crow0 + mt * 16 + quad * 4;  // 4 consecutive tokens
        const long b = tokbase >> 12;
        const long tok = tokbase & 4095;
        const long h = col >> 6, d = col & 63;
        u16x4 pk;
        pk.x = f2b(acc[mt][nt][0] + bv);
        pk.y = f2b(acc[mt][nt][1] + bv);
        pk.z = f2b(acc[mt][nt][2] + bv);
        pk.w = f2b(acc[mt][nt][3] + bv);
        *(u16x4*)((u16*)Cout + ((b * 16 + h) * 64 + d) * (long)SEQ + tok) = pk;
      }
    } else if (mode == 1) {
#pragma unroll
      for (int mt = 0; mt < 4; ++mt)
#pragma unroll
        for (int r = 0; r < 4; ++r) {
          const long row = crow0 + mt * 16 + quad * 4 + r;
          ((float*)Cout)[row * (long)N + col] = acc[mt][nt][r] + bv;
        }
    } else {
#pragma unroll
      for (int mt = 0; mt < 4; ++mt)
#pragma unroll
        for (int r = 0; r < 4; ++r) {
          const long row = crow0 + mt * 16 + quad * 4 + r;
          ((u16*)Cout)[row * (long)N + col] = f2b(acc[mt][nt][r] + bv);
        }
    }
  }
}

// ---------------- windowed attention ----------------
// block = (b, window, head-group of 4, row-half). wave = one head, 32 query rows.
// grid = 2*64*4*2 = 1024 blocks.
__global__ __launch_bounds__(256, 4) void attn_win(
    const u16* __restrict__ qp, const u16* __restrict__ kp,
    const u16* __restrict__ vT, u16* __restrict__ attended,
    float* __restrict__ attn) {
  __shared__ __align__(16) u16 Plds[4][32][72];    // per-wave P (bf16), 18.4 KB

  const int tid = threadIdx.x;
  const int lane = tid & 63;
  const int wave = tid >> 6;
  const int l15 = lane & 15;
  const int quad = lane >> 4;

  const int idx = blockIdx.x;          // (((b*64+n)*4)+hg)*2 + half
  const int half = idx & 1;
  const int hg = (idx >> 1) & 3;
  const int wn = idx >> 3;
  const int b = wn >> 6;
  const int n = wn & 63;
  const int h = hg * 4 + wave;

  const long qrow0 = (long)b * SEQ + (long)n * 64 + half * 32;  // 32 query rows
  const long krow0 = (long)b * SEQ + (long)n * 64;              // all 64 key rows
  const long cbase = (long)h * 64;

  u16(*Pw)[72] = Plds[wave];

  // --- S = Q K^T * scale ---  (32 x 64 tile)
  f32x4 s[2][4];
#pragma unroll
  for (int i = 0; i < 2; ++i)
#pragma unroll
    for (int j = 0; j < 4; ++j) s[i][j] = f32x4{0.f, 0.f, 0.f, 0.f};
#pragma unroll
  for (int kt = 0; kt < 2; ++kt) {
    bf16x8 aq[2], bkf[4];
#pragma unroll
    for (int mt = 0; mt < 2; ++mt)
      aq[mt] = *(const bf16x8*)(qp + (qrow0 + mt * 16 + l15) * HID + cbase + kt * 32 + quad * 8);
#pragma unroll
    for (int nt = 0; nt < 4; ++nt)
      bkf[nt] = *(const bf16x8*)(kp + (krow0 + nt * 16 + l15) * HID + cbase + kt * 32 + quad * 8);
#pragma unroll
    for (int mt = 0; mt < 2; ++mt)
#pragma unroll
      for (int nt = 0; nt < 4; ++nt)
        s[mt][nt] = __builtin_amdgcn_mfma_f32_16x16x32_bf16(aq[mt], bkf[nt], s[mt][nt], 0, 0, 0);
  }

  // --- softmax over 64 keys (cols across 16 lanes x 4 nt) ---
#pragma unroll
  for (int mt = 0; mt < 2; ++mt) {
#pragma unroll
    for (int r = 0; r < 4; ++r) {
      float m = -1e30f;
#pragma unroll
      for (int nt = 0; nt < 4; ++nt) { s[mt][nt][r] *= 0.125f; m = fmaxf(m, s[mt][nt][r]); }
      m = fmaxf(m, __shfl_xor(m, 1));
      m = fmaxf(m, __shfl_xor(m, 2));
      m = fmaxf(m, __shfl_xor(m, 4));
      m = fmaxf(m, __shfl_xor(m, 8));
      float sum = 0.f;
#pragma unroll
      for (int nt = 0; nt < 4; ++nt) { float e = __expf(s[mt][nt][r] - m); s[mt][nt][r] = e; sum += e; }
      sum += __shfl_xor(sum, 1);
      sum += __shfl_xor(sum, 2);
      sum += __shfl_xor(sum, 4);
      sum += __shfl_xor(sum, 8);
      const float inv = 1.f / sum;
#pragma unroll
      for (int nt = 0; nt < 4; ++nt) s[mt][nt][r] *= inv;
    }
  }

  // --- stash P (bf16) for C-layout -> A-layout transform + head mean ---
#pragma unroll
  for (int mt = 0; mt < 2; ++mt)
#pragma unroll
    for (int nt = 0; nt < 4; ++nt)
#pragma unroll
      for (int r = 0; r < 4; ++r)
        Pw[mt * 16 + quad * 4 + r][nt * 16 + l15] = f2b(s[mt][nt][r]);

  // --- O = P V ---  (32 x 64)
  f32x4 o[2][4];
#pragma unroll
  for (int i = 0; i < 2; ++i)
#pragma unroll
    for (int j = 0; j < 4; ++j) o[i][j] = f32x4{0.f, 0.f, 0.f, 0.f};
  const long vbase = ((long)(b * 16 + h) * 64) * SEQ;
#pragma unroll
  for (int kt = 0; kt < 2; ++kt) {
    bf16x8 ap[2], bvf[4];
#pragma unroll
    for (int mt = 0; mt < 2; ++mt)
      ap[mt] = *(const bf16x8*)(&Pw[mt * 16 + l15][kt * 32 + quad * 8]);
#pragma unroll
    for (int nt = 0; nt < 4; ++nt)
      bvf[nt] = *(const bf16x8*)(vT + vbase + (long)(nt * 16 + l15) * SEQ + n * 64 + kt * 32 + quad * 8);
#pragma unroll
    for (int mt = 0; mt < 2; ++mt)
#pragma unroll
      for (int nt = 0; nt < 4; ++nt)
        o[mt][nt] = __builtin_amdgcn_mfma_f32_16x16x32_bf16(ap[mt], bvf[nt], o[mt][nt], 0, 0, 0);
  }

  // --- store attended bf16 [token][h*64+d] ---
#pragma unroll
  for (int mt = 0; mt < 2; ++mt)
#pragma unroll
    for (int nt = 0; nt < 4; ++nt)
#pragma unroll
      for (int r = 0; r < 4; ++r)
        attended[(qrow0 + mt * 16 + quad * 4 + r) * HID + cbase + nt * 16 + l15] = f2b(o[mt][nt][r]);

  // --- head-mean partial: sum this block's 4 heads, atomicAdd into attn diag ---
  __syncthreads();
  float* obase = attn + (long)b * SEQ * SEQ + ((long)n * 64 + half * 32) * SEQ + (long)n * 64;
  for (int i = tid; i < 32 * 64; i += 256) {
    const int r = i >> 6, c = i & 63;
    float sacc = 0.f;
#pragma unroll
    for (int w = 0; w < 4; ++w) sacc += b2f(Plds[w][r][c]);
    atomicAdd(&obase[(long)r * SEQ + c], sacc * (1.f / 16.f));
  }
}

extern "C" void kernel_launch(void* const* d_in, const int* in_sizes, int n_in,
                              void* d_out, int out_size, void* d_ws, size_t ws_size,
                              hipStream_t stream) {
  (void)in_sizes; (void)n_in; (void)out_size; (void)ws_size;
  const float* query = (const float*)d_in[0];
  const float* key   = (const float*)d_in[1];
  const float* value = (const float*)d_in[2];
  const float* Wq = (const float*)d_in[3];
  const float* bq = (const float*)d_in[4];
  const float* Wk = (const float*)d_in[5];
  const float* bk = (const float*)d_in[6];
  const float* Wv = (const float*)d_in[7];
  const float* bv = (const float*)d_in[8];
  const float* Wo = (const float*)d_in[9];
  const float* bo = (const float*)d_in[10];

  float* out  = (float*)d_out;
  float* attn = out + (size_t)BATCH * SEQ * HID;   // +8388608 floats

  char* ws = (char*)d_ws;
  const size_t MB = (size_t)1 << 20;
  u16* xq = (u16*)(ws + 0 * MB);    // later reused as 'attended'
  u16* xk = (u16*)(ws + 16 * MB);   // later reused as vT
  u16* xv = (u16*)(ws + 32 * MB);
  u16* wq = (u16*)(ws + 48 * MB);
  u16* wk = (u16*)(ws + 50 * MB);
  u16* wv = (u16*)(ws + 52 * MB);
  u16* wo = (u16*)(ws + 54 * MB);
  u16* qp = (u16*)(ws + 56 * MB);
  u16* kp = (u16*)(ws + 72 * MB);
  u16* vT  = xk;   // dead after K-projection
  u16* att = xq;   // dead after Q-projection

  // zero the (block-diagonal) attention map; diag blocks accumulated by attn_win
  hipMemsetAsync(attn, 0, (size_t)BATCH * SEQ * SEQ * sizeof(float), stream);

  cvt_all<<<3584, 256, 0, stream>>>(query, key, value, Wq, Wk, Wv, Wo,
                                    xq, xk, xv, wq, wk, wv, wo);

  Gemm3Args ga;
  ga.A[0] = xq; ga.W[0] = wq; ga.bias[0] = bq; ga.C[0] = qp; ga.mode[0] = 0;
  ga.A[1] = xk; ga.W[1] = wk; ga.bias[1] = bk; ga.C[1] = kp; ga.mode[1] = 0;
  ga.A[2] = xv; ga.W[2] = wv; ga.bias[2] = bv; ga.C[2] = vT; ga.mode[2] = 2;
  dim3 g3(HID / 128, (BATCH * SEQ) / 128, 3);  // (8, 64, 3)
  gemm_bt_fused<<<g3, 256, 0, stream>>>(ga);

  attn_win<<<BATCH * 64 * 4 * 2, 256, 0, stream>>>(qp, kp, vT, att, attn);

  Gemm3Args go;
  go.A[0] = att; go.W[0] = wo; go.bias[0] = bo; go.C[0] = out; go.mode[0] = 1;
  go.A[1] = att; go.W[1] = wo; go.bias[1] = bo; go.C[1] = out; go.mode[1] = 1;
  go.A[2] = att; go.W[2] = wo; go.bias[2] = bo; go.C[2] = out; go.mode[2] = 1;
  dim3 g1(HID / 128, (BATCH * SEQ) / 128, 1);  // (8, 64, 1)
  gemm_bt_fused<<<g1, 256, 0, stream>>>(go);
}

// Round 4
// 407.006 us; speedup vs baseline: 1.2420x; 1.0237x over previous
//
#include <hip/hip_runtime.h>

typedef unsigned short u16;
typedef unsigned int u32;
typedef __attribute__((ext_vector_type(8))) short bf16x8;   // 8 bf16 in 4 VGPRs
typedef __attribute__((ext_vector_type(4))) float f32x4;
typedef __attribute__((ext_vector_type(4))) u16 u16x4;

typedef __attribute__((address_space(1))) unsigned int as1_u32;
typedef __attribute__((address_space(3))) unsigned int as3_u32;

#define SEQ 4096
#define HID 1024
#define NHEAD 16
#define BATCH 2

__device__ __forceinline__ u16 f2b(float f) {
  union { float f; u32 u; } v; v.f = f;
  u32 r = v.u + 0x7FFFu + ((v.u >> 16) & 1u);   // RNE
  return (u16)(r >> 16);
}

__device__ __forceinline__ float b2f(u16 b) {
  union { u32 u; float f; } v; v.u = ((u32)b) << 16;
  return v.f;
}

__device__ __forceinline__ void async_cp16(const void* g, void* l) {
  __builtin_amdgcn_global_load_lds((const as1_u32*)g, (as3_u32*)l, 16, 0, 0);
}

// ---------------- fp32 -> bf16 convert (all 7 tensors, one launch) ----------------
__global__ __launch_bounds__(256) void cvt_all(
    const float* __restrict__ q, const float* __restrict__ k, const float* __restrict__ v,
    const float* __restrict__ Wq, const float* __restrict__ Wk,
    const float* __restrict__ Wv, const float* __restrict__ Wo,
    u16* __restrict__ xq, u16* __restrict__ xk, u16* __restrict__ xv,
    u16* __restrict__ wq, u16* __restrict__ wk, u16* __restrict__ wv, u16* __restrict__ wo) {
  const int total = (3 << 21) + (4 << 18);   // 7,340,032 float4 groups
  for (int i = blockIdx.x * blockDim.x + threadIdx.x; i < total; i += gridDim.x * blockDim.x) {
    const float* src; u16* dst; int j;
    if (i < (3 << 21)) {
      const int sel = i >> 21; j = i & ((1 << 21) - 1);
      src = sel == 0 ? q : (sel == 1 ? k : v);
      dst = sel == 0 ? xq : (sel == 1 ? xk : xv);
    } else {
      const int ii = i - (3 << 21);
      const int sel = ii >> 18; j = ii & ((1 << 18) - 1);
      src = sel == 0 ? Wq : (sel == 1 ? Wk : (sel == 2 ? Wv : Wo));
      dst = sel == 0 ? wq : (sel == 1 ? wk : (sel == 2 ? wv : wo));
    }
    float4 f = ((const float4*)src)[j];
    u16x4 o; o.x = f2b(f.x); o.y = f2b(f.y); o.z = f2b(f.z); o.w = f2b(f.w);
    ((u16x4*)dst)[j] = o;
  }
}

// ---------------- GEMM: C = A[8192x1024] * Bw[1024x1024]^T + bias ----------------
// mode 0: bf16 row-major out. mode 2: bf16 transposed out -> vT[(b*16+h)*64+d][token]
struct Gemm3Args {
  const u16* A[3]; const u16* W[3]; const float* bias[3]; void* C[3]; int mode[3];
};

__global__ __launch_bounds__(256, 2) void gemm_bt_fused(Gemm3Args ga) {
  __shared__ __align__(16) u16 As[128 * 32];
  __shared__ __align__(16) u16 Bs[128 * 32];

  const int z = blockIdx.z;
  const u16* __restrict__ A  = ga.A[z];
  const u16* __restrict__ Bw = ga.W[z];
  const float* __restrict__ bias = ga.bias[z];
  void* __restrict__ Cout = ga.C[z];
  const int mode = ga.mode[z];
  const int K = HID, N = HID;

  const int tid = threadIdx.x;
  const int lane = tid & 63;
  const int wave = tid >> 6;
  const int l15 = lane & 15;
  const int quad = lane >> 4;
  const int wr = wave >> 1;
  const int wc = wave & 1;
  const long brow = (long)blockIdx.y * 128;
  const long bcol = (long)blockIdx.x * 128;

  const int srow = lane >> 2;          // row within 16-row chunk
  const int scol = (lane & 3) * 8;     // bf16 elems (16B)
  const u16* Ag0 = A + (brow + wave * 16 + srow) * (long)K + scol;
  const u16* Ag1 = A + (brow + (wave + 4) * 16 + srow) * (long)K + scol;
  const u16* Bg0 = Bw + (bcol + wave * 16 + srow) * (long)K + scol;
  const u16* Bg1 = Bw + (bcol + (wave + 4) * 16 + srow) * (long)K + scol;
  u16* Al0 = As + wave * 512;          // wave-uniform LDS bases (HW adds lane*16B)
  u16* Al1 = As + (wave + 4) * 512;
  u16* Bl0 = Bs + wave * 512;
  u16* Bl1 = Bs + (wave + 4) * 512;

  f32x4 acc[4][4];
#pragma unroll
  for (int i = 0; i < 4; ++i)
#pragma unroll
    for (int j = 0; j < 4; ++j) acc[i][j] = f32x4{0.f, 0.f, 0.f, 0.f};

  const u16* Afb = As + (wr * 64 + l15) * 32 + quad * 8;
  const u16* Bfb = Bs + (wc * 64 + l15) * 32 + quad * 8;

  for (int k0 = 0; k0 < K; k0 += 32) {
    async_cp16(Ag0 + k0, Al0);
    async_cp16(Ag1 + k0, Al1);
    async_cp16(Bg0 + k0, Bl0);
    async_cp16(Bg1 + k0, Bl1);
    __syncthreads();
    bf16x8 af[4], bfv[4];
#pragma unroll
    for (int mt = 0; mt < 4; ++mt) af[mt] = *(const bf16x8*)(Afb + mt * 512);
#pragma unroll
    for (int nt = 0; nt < 4; ++nt) bfv[nt] = *(const bf16x8*)(Bfb + nt * 512);
#pragma unroll
    for (int mt = 0; mt < 4; ++mt)
#pragma unroll
      for (int nt = 0; nt < 4; ++nt)
        acc[mt][nt] = __builtin_amdgcn_mfma_f32_16x16x32_bf16(af[mt], bfv[nt], acc[mt][nt], 0, 0, 0);
    __syncthreads();
  }

  const long crow0 = brow + wr * 64;
  const long ccol0 = bcol + wc * 64;
#pragma unroll
  for (int nt = 0; nt < 4; ++nt) {
    const long col = ccol0 + nt * 16 + l15;
    const float bv = bias[col];
    if (mode == 2) {
#pragma unroll
      for (int mt = 0; mt < 4; ++mt) {
        const long tokbase = crow0 + mt * 16 + quad * 4;  // 4 consecutive tokens
        const long b = tokbase >> 12;
        const long tok = tokbase & 4095;
        const long h = col >> 6, d = col & 63;
        u16x4 pk;
        pk.x = f2b(acc[mt][nt][0] + bv);
        pk.y = f2b(acc[mt][nt][1] + bv);
        pk.z = f2b(acc[mt][nt][2] + bv);
        pk.w = f2b(acc[mt][nt][3] + bv);
        *(u16x4*)((u16*)Cout + ((b * 16 + h) * 64 + d) * (long)SEQ + tok) = pk;
      }
    } else {
#pragma unroll
      for (int mt = 0; mt < 4; ++mt)
#pragma unroll
        for (int r = 0; r < 4; ++r) {
          const long row = crow0 + mt * 16 + quad * 4 + r;
          ((u16*)Cout)[row * (long)N + col] = f2b(acc[mt][nt][r] + bv);
        }
    }
  }
}

// ---------------- windowed attention ----------------
// block = (b, window, head-group of 4, row-half). wave = one head, 32 query rows.
// grid = 2*64*4*2 = 1024 blocks. Writes attended + per-block 4-head P partial sum.
__global__ __launch_bounds__(256, 4) void attn_win(
    const u16* __restrict__ qp, const u16* __restrict__ kp,
    const u16* __restrict__ vT, u16* __restrict__ attended,
    float* __restrict__ Psum) {
  __shared__ __align__(16) u16 Plds[4][32][72];    // per-wave P (bf16), 18.4 KB

  const int tid = threadIdx.x;
  const int lane = tid & 63;
  const int wave = tid >> 6;
  const int l15 = lane & 15;
  const int quad = lane >> 4;

  const int idx = blockIdx.x;          // (((b*64+n)*4)+hg)*2 + half
  const int half = idx & 1;
  const int hg = (idx >> 1) & 3;
  const int wn = idx >> 3;
  const int b = wn >> 6;
  const int n = wn & 63;
  const int h = hg * 4 + wave;

  const long qrow0 = (long)b * SEQ + (long)n * 64 + half * 32;  // 32 query rows
  const long krow0 = (long)b * SEQ + (long)n * 64;              // all 64 key rows
  const long cbase = (long)h * 64;

  u16(*Pw)[72] = Plds[wave];

  // --- S = Q K^T * scale ---  (32 x 64 tile)
  f32x4 s[2][4];
#pragma unroll
  for (int i = 0; i < 2; ++i)
#pragma unroll
    for (int j = 0; j < 4; ++j) s[i][j] = f32x4{0.f, 0.f, 0.f, 0.f};
#pragma unroll
  for (int kt = 0; kt < 2; ++kt) {
    bf16x8 aq[2], bkf[4];
#pragma unroll
    for (int mt = 0; mt < 2; ++mt)
      aq[mt] = *(const bf16x8*)(qp + (qrow0 + mt * 16 + l15) * HID + cbase + kt * 32 + quad * 8);
#pragma unroll
    for (int nt = 0; nt < 4; ++nt)
      bkf[nt] = *(const bf16x8*)(kp + (krow0 + nt * 16 + l15) * HID + cbase + kt * 32 + quad * 8);
#pragma unroll
    for (int mt = 0; mt < 2; ++mt)
#pragma unroll
      for (int nt = 0; nt < 4; ++nt)
        s[mt][nt] = __builtin_amdgcn_mfma_f32_16x16x32_bf16(aq[mt], bkf[nt], s[mt][nt], 0, 0, 0);
  }

  // --- softmax over 64 keys (cols across 16 lanes x 4 nt) ---
#pragma unroll
  for (int mt = 0; mt < 2; ++mt) {
#pragma unroll
    for (int r = 0; r < 4; ++r) {
      float m = -1e30f;
#pragma unroll
      for (int nt = 0; nt < 4; ++nt) { s[mt][nt][r] *= 0.125f; m = fmaxf(m, s[mt][nt][r]); }
      m = fmaxf(m, __shfl_xor(m, 1));
      m = fmaxf(m, __shfl_xor(m, 2));
      m = fmaxf(m, __shfl_xor(m, 4));
      m = fmaxf(m, __shfl_xor(m, 8));
      float sum = 0.f;
#pragma unroll
      for (int nt = 0; nt < 4; ++nt) { float e = __expf(s[mt][nt][r] - m); s[mt][nt][r] = e; sum += e; }
      sum += __shfl_xor(sum, 1);
      sum += __shfl_xor(sum, 2);
      sum += __shfl_xor(sum, 4);
      sum += __shfl_xor(sum, 8);
      const float inv = 1.f / sum;
#pragma unroll
      for (int nt = 0; nt < 4; ++nt) s[mt][nt][r] *= inv;
    }
  }

  // --- stash P (bf16) for C-layout -> A-layout transform + head-mean partial ---
#pragma unroll
  for (int mt = 0; mt < 2; ++mt)
#pragma unroll
    for (int nt = 0; nt < 4; ++nt)
#pragma unroll
      for (int r = 0; r < 4; ++r)
        Pw[mt * 16 + quad * 4 + r][nt * 16 + l15] = f2b(s[mt][nt][r]);

  // --- O = P V ---  (32 x 64)
  f32x4 o[2][4];
#pragma unroll
  for (int i = 0; i < 2; ++i)
#pragma unroll
    for (int j = 0; j < 4; ++j) o[i][j] = f32x4{0.f, 0.f, 0.f, 0.f};
  const long vbase = ((long)(b * 16 + h) * 64) * SEQ;
#pragma unroll
  for (int kt = 0; kt < 2; ++kt) {
    bf16x8 ap[2], bvf[4];
#pragma unroll
    for (int mt = 0; mt < 2; ++mt)
      ap[mt] = *(const bf16x8*)(&Pw[mt * 16 + l15][kt * 32 + quad * 8]);
#pragma unroll
    for (int nt = 0; nt < 4; ++nt)
      bvf[nt] = *(const bf16x8*)(vT + vbase + (long)(nt * 16 + l15) * SEQ + n * 64 + kt * 32 + quad * 8);
#pragma unroll
    for (int mt = 0; mt < 2; ++mt)
#pragma unroll
      for (int nt = 0; nt < 4; ++nt)
        o[mt][nt] = __builtin_amdgcn_mfma_f32_16x16x32_bf16(ap[mt], bvf[nt], o[mt][nt], 0, 0, 0);
  }

  // --- store attended bf16 [token][h*64+d] ---
#pragma unroll
  for (int mt = 0; mt < 2; ++mt)
#pragma unroll
    for (int nt = 0; nt < 4; ++nt)
#pragma unroll
      for (int r = 0; r < 4; ++r)
        attended[(qrow0 + mt * 16 + quad * 4 + r) * HID + cbase + nt * 16 + l15] = f2b(o[mt][nt][r]);

  // --- head-mean partial: sum this block's 4 heads -> Psum[block][32][64] ---
  __syncthreads();
  float* pbase = Psum + (long)idx * 2048;
  for (int i = tid; i < 32 * 64; i += 256) {
    const int r = i >> 6, c = i & 63;
    float sacc = 0.f;
#pragma unroll
    for (int w = 0; w < 4; ++w) sacc += b2f(Plds[w][r][c]);
    pbase[i] = sacc;
  }
}

// ---------------- fused O-projection GEMM + attn-map expand ----------------
// blocks 0..511: out = att * Wo^T + bo (fp32). blocks 512..2559: write attn map
// (zeros everywhere, diagonal 64x64 blocks = mean over heads from Psum).
__global__ __launch_bounds__(256, 2) void gemm_o_expand(
    const u16* __restrict__ A, const u16* __restrict__ Bw,
    const float* __restrict__ bias, float* __restrict__ Cout,
    const float* __restrict__ Psum, float* __restrict__ attn) {
  __shared__ __align__(16) u16 As[128 * 32];
  __shared__ __align__(16) u16 Bs[128 * 32];

  const int tid = threadIdx.x;

  if (blockIdx.x >= 512) {
    // ---- expand path: 2048 blocks x 4096 float4 each ----
    const long e = blockIdx.x - 512;
    const long f0 = e * 4096;
#pragma unroll
    for (int it = 0; it < 16; ++it) {
      const long f = f0 + it * 256 + tid;              // float4 index into attn
      const int b = (int)(f >> 22);                    // 2^22 float4 per batch
      const int rem = (int)(f & ((1 << 22) - 1));
      const int row = rem >> 10;                       // 1024 float4 per row
      const int c4 = rem & 1023;
      const int n = row >> 6;
      float4 val = {0.f, 0.f, 0.f, 0.f};
      const int d4 = c4 - n * 16;                      // diag cols = [n*64, n*64+64)
      if ((unsigned)d4 < 16u) {
        const int r = row & 63;
        const int half = r >> 5, rr = r & 31;
        const long base = ((long)((b * 64 + n) * 8 + half)) * 2048 + rr * 64 + d4 * 4;
        float4 p0 = *(const float4*)(Psum + base);
        float4 p1 = *(const float4*)(Psum + base + 4096);
        float4 p2 = *(const float4*)(Psum + base + 8192);
        float4 p3 = *(const float4*)(Psum + base + 12288);
        val.x = (p0.x + p1.x + p2.x + p3.x) * (1.f / 16.f);
        val.y = (p0.y + p1.y + p2.y + p3.y) * (1.f / 16.f);
        val.z = (p0.z + p1.z + p2.z + p3.z) * (1.f / 16.f);
        val.w = (p0.w + p1.w + p2.w + p3.w) * (1.f / 16.f);
      }
      ((float4*)attn)[f] = val;
    }
    return;
  }

  // ---- GEMM path: 512 blocks (8 x 64) ----
  const int lane = tid & 63;
  const int wave = tid >> 6;
  const int l15 = lane & 15;
  const int quad = lane >> 4;
  const int wr = wave >> 1;
  const int wc = wave & 1;
  const long brow = (long)(blockIdx.x >> 3) * 128;
  const long bcol = (long)(blockIdx.x & 7) * 128;
  const int K = HID, N = HID;

  const int srow = lane >> 2;
  const int scol = (lane & 3) * 8;
  const u16* Ag0 = A + (brow + wave * 16 + srow) * (long)K + scol;
  const u16* Ag1 = A + (brow + (wave + 4) * 16 + srow) * (long)K + scol;
  const u16* Bg0 = Bw + (bcol + wave * 16 + srow) * (long)K + scol;
  const u16* Bg1 = Bw + (bcol + (wave + 4) * 16 + srow) * (long)K + scol;
  u16* Al0 = As + wave * 512;
  u16* Al1 = As + (wave + 4) * 512;
  u16* Bl0 = Bs + wave * 512;
  u16* Bl1 = Bs + (wave + 4) * 512;

  f32x4 acc[4][4];
#pragma unroll
  for (int i = 0; i < 4; ++i)
#pragma unroll
    for (int j = 0; j < 4; ++j) acc[i][j] = f32x4{0.f, 0.f, 0.f, 0.f};

  const u16* Afb = As + (wr * 64 + l15) * 32 + quad * 8;
  const u16* Bfb = Bs + (wc * 64 + l15) * 32 + quad * 8;

  for (int k0 = 0; k0 < K; k0 += 32) {
    async_cp16(Ag0 + k0, Al0);
    async_cp16(Ag1 + k0, Al1);
    async_cp16(Bg0 + k0, Bl0);
    async_cp16(Bg1 + k0, Bl1);
    __syncthreads();
    bf16x8 af[4], bfv[4];
#pragma unroll
    for (int mt = 0; mt < 4; ++mt) af[mt] = *(const bf16x8*)(Afb + mt * 512);
#pragma unroll
    for (int nt = 0; nt < 4; ++nt) bfv[nt] = *(const bf16x8*)(Bfb + nt * 512);
#pragma unroll
    for (int mt = 0; mt < 4; ++mt)
#pragma unroll
      for (int nt = 0; nt < 4; ++nt)
        acc[mt][nt] = __builtin_amdgcn_mfma_f32_16x16x32_bf16(af[mt], bfv[nt], acc[mt][nt], 0, 0, 0);
    __syncthreads();
  }

  const long crow0 = brow + wr * 64;
  const long ccol0 = bcol + wc * 64;
#pragma unroll
  for (int nt = 0; nt < 4; ++nt) {
    const long col = ccol0 + nt * 16 + l15;
    const float bv = bias[col];
#pragma unroll
    for (int mt = 0; mt < 4; ++mt)
#pragma unroll
      for (int r = 0; r < 4; ++r) {
        const long row = crow0 + mt * 16 + quad * 4 + r;
        Cout[row * (long)N + col] = acc[mt][nt][r] + bv;
      }
  }
}

extern "C" void kernel_launch(void* const* d_in, const int* in_sizes, int n_in,
                              void* d_out, int out_size, void* d_ws, size_t ws_size,
                              hipStream_t stream) {
  (void)in_sizes; (void)n_in; (void)out_size; (void)ws_size;
  const float* query = (const float*)d_in[0];
  const float* key   = (const float*)d_in[1];
  const float* value = (const float*)d_in[2];
  const float* Wq = (const float*)d_in[3];
  const float* bq = (const float*)d_in[4];
  const float* Wk = (const float*)d_in[5];
  const float* bk = (const float*)d_in[6];
  const float* Wv = (const float*)d_in[7];
  const float* bv = (const float*)d_in[8];
  const float* Wo = (const float*)d_in[9];
  const float* bo = (const float*)d_in[10];

  float* out  = (float*)d_out;
  float* attn = out + (size_t)BATCH * SEQ * HID;   // +8388608 floats

  char* ws = (char*)d_ws;
  const size_t MB = (size_t)1 << 20;
  // Workspace map (NO overlaps — vT is 16 MB: 88..104):
  //   xq 0-16 | xk 16-32 | xv 32-48 | wq/wk/wv/wo 48-56 | qp 56-72 | kp 72-88
  //   vT 88-104 | Psum 104-112
  u16* xq = (u16*)(ws + 0 * MB);    // later reused as 'attended'
  u16* xk = (u16*)(ws + 16 * MB);
  u16* xv = (u16*)(ws + 32 * MB);
  u16* wq = (u16*)(ws + 48 * MB);
  u16* wk = (u16*)(ws + 50 * MB);
  u16* wv = (u16*)(ws + 52 * MB);
  u16* wo = (u16*)(ws + 54 * MB);
  u16* qp = (u16*)(ws + 56 * MB);
  u16* kp = (u16*)(ws + 72 * MB);
  u16* vT = (u16*)(ws + 88 * MB);        // 16 MB: spans 88..104
  float* Psum = (float*)(ws + 104 * MB); // 8 MB: 104..112 (was 96 -> overlapped vT b=1!)
  u16* att = xq;   // dead after gemm3 completes (attn_win runs strictly after)

  cvt_all<<<3584, 256, 0, stream>>>(query, key, value, Wq, Wk, Wv, Wo,
                                    xq, xk, xv, wq, wk, wv, wo);

  Gemm3Args ga;
  ga.A[0] = xq; ga.W[0] = wq; ga.bias[0] = bq; ga.C[0] = qp; ga.mode[0] = 0;
  ga.A[1] = xk; ga.W[1] = wk; ga.bias[1] = bk; ga.C[1] = kp; ga.mode[1] = 0;
  ga.A[2] = xv; ga.W[2] = wv; ga.bias[2] = bv; ga.C[2] = vT; ga.mode[2] = 2;
  dim3 g3(HID / 128, (BATCH * SEQ) / 128, 3);  // (8, 64, 3)
  gemm_bt_fused<<<g3, 256, 0, stream>>>(ga);

  attn_win<<<BATCH * 64 * 4 * 2, 256, 0, stream>>>(qp, kp, vT, att, Psum);

  gemm_o_expand<<<512 + 2048, 256, 0, stream>>>(att, wo, bo, out, Psum, attn);
}

// Round 5
// 390.032 us; speedup vs baseline: 1.2961x; 1.0435x over previous
//
#include <hip/hip_runtime.h>

typedef unsigned short u16;
typedef unsigned int u32;
typedef __attribute__((ext_vector_type(8))) short bf16x8;   // 8 bf16 in 4 VGPRs
typedef __attribute__((ext_vector_type(4))) float f32x4;
typedef __attribute__((ext_vector_type(4))) u16 u16x4;

typedef __attribute__((address_space(1))) unsigned int as1_u32;
typedef __attribute__((address_space(3))) unsigned int as3_u32;

#define SEQ 4096
#define HID 1024
#define NHEAD 16
#define BATCH 2

__device__ __forceinline__ u16 f2b(float f) {
  union { float f; u32 u; } v; v.f = f;
  u32 r = v.u + 0x7FFFu + ((v.u >> 16) & 1u);   // RNE
  return (u16)(r >> 16);
}

__device__ __forceinline__ float b2f(u16 b) {
  union { u32 u; float f; } v; v.u = ((u32)b) << 16;
  return v.f;
}

__device__ __forceinline__ void async_cp16(const void* g, void* l) {
  __builtin_amdgcn_global_load_lds((const as1_u32*)g, (as3_u32*)l, 16, 0, 0);
}

// ---------------- fp32 -> bf16 convert (all 7 tensors, one launch) ----------------
__global__ __launch_bounds__(256) void cvt_all(
    const float* __restrict__ q, const float* __restrict__ k, const float* __restrict__ v,
    const float* __restrict__ Wq, const float* __restrict__ Wk,
    const float* __restrict__ Wv, const float* __restrict__ Wo,
    u16* __restrict__ xq, u16* __restrict__ xk, u16* __restrict__ xv,
    u16* __restrict__ wq, u16* __restrict__ wk, u16* __restrict__ wv, u16* __restrict__ wo) {
  const int total = (3 << 21) + (4 << 18);   // 7,340,032 float4 groups
  for (int i = blockIdx.x * blockDim.x + threadIdx.x; i < total; i += gridDim.x * blockDim.x) {
    const float* src; u16* dst; int j;
    if (i < (3 << 21)) {
      const int sel = i >> 21; j = i & ((1 << 21) - 1);
      src = sel == 0 ? q : (sel == 1 ? k : v);
      dst = sel == 0 ? xq : (sel == 1 ? xk : xv);
    } else {
      const int ii = i - (3 << 21);
      const int sel = ii >> 18; j = ii & ((1 << 18) - 1);
      src = sel == 0 ? Wq : (sel == 1 ? Wk : (sel == 2 ? Wv : Wo));
      dst = sel == 0 ? wq : (sel == 1 ? wk : (sel == 2 ? wv : wo));
    }
    float4 f = ((const float4*)src)[j];
    u16x4 o; o.x = f2b(f.x); o.y = f2b(f.y); o.z = f2b(f.z); o.w = f2b(f.w);
    ((u16x4*)dst)[j] = o;
  }
}

// ---------------- GEMM core: C = A[8192x1024] * Bw[1024x1024]^T + bias ----------------
// MODE 0: bf16 row-major out (operand-SWAPPED mfma -> vectorized row stores)
// MODE 1: fp32 row-major out (swapped, float4 stores)
// MODE 2: bf16 transposed out -> vT[(b*16+h)*64+d][token] (unswapped: regs = tokens)
template <int MODE>
__device__ __forceinline__ void gemm_core(
    const u16* __restrict__ A, const u16* __restrict__ Bw,
    const float* __restrict__ bias, void* __restrict__ Cout,
    u16* As, u16* Bs, long brow, long bcol) {
  const int K = HID, N = HID;
  const int tid = threadIdx.x;
  const int lane = tid & 63;
  const int wave = tid >> 6;
  const int l15 = lane & 15;
  const int quad = lane >> 4;
  const int wr = wave >> 1;
  const int wc = wave & 1;

  const int srow = lane >> 2;          // row within 16-row chunk
  const int scol = (lane & 3) * 8;     // bf16 elems (16B)
  const u16* Ag0 = A + (brow + wave * 16 + srow) * (long)K + scol;
  const u16* Ag1 = A + (brow + (wave + 4) * 16 + srow) * (long)K + scol;
  const u16* Bg0 = Bw + (bcol + wave * 16 + srow) * (long)K + scol;
  const u16* Bg1 = Bw + (bcol + (wave + 4) * 16 + srow) * (long)K + scol;
  u16* Al0 = As + wave * 512;          // wave-uniform LDS bases (HW adds lane*16B)
  u16* Al1 = As + (wave + 4) * 512;
  u16* Bl0 = Bs + wave * 512;
  u16* Bl1 = Bs + (wave + 4) * 512;

  f32x4 acc[4][4];
#pragma unroll
  for (int i = 0; i < 4; ++i)
#pragma unroll
    for (int j = 0; j < 4; ++j) acc[i][j] = f32x4{0.f, 0.f, 0.f, 0.f};

  const u16* Afb = As + (wr * 64 + l15) * 32 + quad * 8;
  const u16* Bfb = Bs + (wc * 64 + l15) * 32 + quad * 8;

  for (int k0 = 0; k0 < K; k0 += 32) {
    async_cp16(Ag0 + k0, Al0);
    async_cp16(Ag1 + k0, Al1);
    async_cp16(Bg0 + k0, Bl0);
    async_cp16(Bg1 + k0, Bl1);
    __syncthreads();
    bf16x8 af[4], bfv[4];
#pragma unroll
    for (int mt = 0; mt < 4; ++mt) af[mt] = *(const bf16x8*)(Afb + mt * 512);
#pragma unroll
    for (int nt = 0; nt < 4; ++nt) bfv[nt] = *(const bf16x8*)(Bfb + nt * 512);
#pragma unroll
    for (int mt = 0; mt < 4; ++mt)
#pragma unroll
      for (int nt = 0; nt < 4; ++nt) {
        if (MODE == 2)
          acc[mt][nt] = __builtin_amdgcn_mfma_f32_16x16x32_bf16(af[mt], bfv[nt], acc[mt][nt], 0, 0, 0);
        else  // swapped: D^T -> rows(N) on quad/reg, cols(M) on l15
          acc[mt][nt] = __builtin_amdgcn_mfma_f32_16x16x32_bf16(bfv[nt], af[mt], acc[mt][nt], 0, 0, 0);
      }
    __syncthreads();
  }

  const long crow0 = brow + wr * 64;
  const long ccol0 = bcol + wc * 64;

  if (MODE == 2) {
#pragma unroll
    for (int nt = 0; nt < 4; ++nt) {
      const long col = ccol0 + nt * 16 + l15;
      const float bv = bias[col];
#pragma unroll
      for (int mt = 0; mt < 4; ++mt) {
        const long tokbase = crow0 + mt * 16 + quad * 4;  // 4 consecutive tokens
        const long b = tokbase >> 12;
        const long tok = tokbase & 4095;
        const long h = col >> 6, d = col & 63;
        u16x4 pk;
        pk.x = f2b(acc[mt][nt][0] + bv);
        pk.y = f2b(acc[mt][nt][1] + bv);
        pk.z = f2b(acc[mt][nt][2] + bv);
        pk.w = f2b(acc[mt][nt][3] + bv);
        *(u16x4*)((u16*)Cout + ((b * 16 + h) * 64 + d) * (long)SEQ + tok) = pk;
      }
    }
  } else {
    // swapped layout: value acc[mt][nt][r] = C[crow0+mt*16+l15][ccol0+nt*16+quad*4+r]
#pragma unroll
    for (int nt = 0; nt < 4; ++nt) {
      const long colb = ccol0 + nt * 16 + quad * 4;
      const float4 b4 = *(const float4*)(bias + colb);
#pragma unroll
      for (int mt = 0; mt < 4; ++mt) {
        const long row = crow0 + mt * 16 + l15;
        if (MODE == 1) {
          float4 v;
          v.x = acc[mt][nt][0] + b4.x;
          v.y = acc[mt][nt][1] + b4.y;
          v.z = acc[mt][nt][2] + b4.z;
          v.w = acc[mt][nt][3] + b4.w;
          *(float4*)((float*)Cout + row * (long)N + colb) = v;
        } else {
          u16x4 pk;
          pk.x = f2b(acc[mt][nt][0] + b4.x);
          pk.y = f2b(acc[mt][nt][1] + b4.y);
          pk.z = f2b(acc[mt][nt][2] + b4.z);
          pk.w = f2b(acc[mt][nt][3] + b4.w);
          *(u16x4*)((u16*)Cout + row * (long)N + colb) = pk;
        }
      }
    }
  }
}

struct Gemm3Args {
  const u16* A[3]; const u16* W[3]; const float* bias[3]; void* C[3]; int mode[3];
};

__global__ __launch_bounds__(256, 2) void gemm_bt_fused(Gemm3Args ga) {
  __shared__ __align__(16) u16 As[128 * 32];
  __shared__ __align__(16) u16 Bs[128 * 32];
  const int z = blockIdx.z;
  const long brow = (long)blockIdx.y * 128;
  const long bcol = (long)blockIdx.x * 128;
  if (ga.mode[z] == 2)
    gemm_core<2>(ga.A[z], ga.W[z], ga.bias[z], ga.C[z], As, Bs, brow, bcol);
  else
    gemm_core<0>(ga.A[z], ga.W[z], ga.bias[z], ga.C[z], As, Bs, brow, bcol);
}

// ---------------- windowed attention ----------------
// block = (b, window, head-group of 4, row-half). wave = one head, 32 query rows.
// grid = 2*64*4*2 = 1024 blocks. Swapped-operand MFMA throughout:
//   S' tile: key on quad/reg, query on l15  -> softmax = 16 in-reg vals + 2 shuffles
//   O' tile: d on quad/reg, token on l15    -> u16x4 attended stores
__global__ __launch_bounds__(256, 4) void attn_win(
    const u16* __restrict__ qp, const u16* __restrict__ kp,
    const u16* __restrict__ vT, u16* __restrict__ attended,
    float* __restrict__ Psum) {
  __shared__ __align__(16) u16 Plds[4][32][72];    // per-wave P (bf16) [query][key]

  const int tid = threadIdx.x;
  const int lane = tid & 63;
  const int wave = tid >> 6;
  const int l15 = lane & 15;
  const int quad = lane >> 4;

  const int idx = blockIdx.x;          // (((b*64+n)*4)+hg)*2 + half
  const int half = idx & 1;
  const int hg = (idx >> 1) & 3;
  const int wn = idx >> 3;
  const int b = wn >> 6;
  const int n = wn & 63;
  const int h = hg * 4 + wave;

  const long qrow0 = (long)b * SEQ + (long)n * 64 + half * 32;  // 32 query rows
  const long krow0 = (long)b * SEQ + (long)n * 64;              // all 64 key rows
  const long cbase = (long)h * 64;

  u16(*Pw)[72] = Plds[wave];

  // --- S' = (K Q^T): s[mt][nt][reg]: key = nt*16+quad*4+reg, query = mt*16+l15 ---
  f32x4 s[2][4];
#pragma unroll
  for (int i = 0; i < 2; ++i)
#pragma unroll
    for (int j = 0; j < 4; ++j) s[i][j] = f32x4{0.f, 0.f, 0.f, 0.f};
#pragma unroll
  for (int kt = 0; kt < 2; ++kt) {
    bf16x8 aq[2], bkf[4];
#pragma unroll
    for (int mt = 0; mt < 2; ++mt)
      aq[mt] = *(const bf16x8*)(qp + (qrow0 + mt * 16 + l15) * HID + cbase + kt * 32 + quad * 8);
#pragma unroll
    for (int nt = 0; nt < 4; ++nt)
      bkf[nt] = *(const bf16x8*)(kp + (krow0 + nt * 16 + l15) * HID + cbase + kt * 32 + quad * 8);
#pragma unroll
    for (int mt = 0; mt < 2; ++mt)
#pragma unroll
      for (int nt = 0; nt < 4; ++nt)
        s[mt][nt] = __builtin_amdgcn_mfma_f32_16x16x32_bf16(bkf[nt], aq[mt], s[mt][nt], 0, 0, 0);
  }

  // --- softmax over 64 keys: 16 in-lane values (nt x reg) + quad reduce ---
#pragma unroll
  for (int mt = 0; mt < 2; ++mt) {
    float m = -1e30f;
#pragma unroll
    for (int nt = 0; nt < 4; ++nt)
#pragma unroll
      for (int r = 0; r < 4; ++r) { s[mt][nt][r] *= 0.125f; m = fmaxf(m, s[mt][nt][r]); }
    m = fmaxf(m, __shfl_xor(m, 16));
    m = fmaxf(m, __shfl_xor(m, 32));
    float sum = 0.f;
#pragma unroll
    for (int nt = 0; nt < 4; ++nt)
#pragma unroll
      for (int r = 0; r < 4; ++r) { float e = __expf(s[mt][nt][r] - m); s[mt][nt][r] = e; sum += e; }
    sum += __shfl_xor(sum, 16);
    sum += __shfl_xor(sum, 32);
    const float inv = 1.f / sum;
#pragma unroll
    for (int nt = 0; nt < 4; ++nt)
#pragma unroll
      for (int r = 0; r < 4; ++r) s[mt][nt][r] *= inv;
  }

  // --- stash P (bf16) [query][key], vectorized u16x4 writes ---
#pragma unroll
  for (int mt = 0; mt < 2; ++mt)
#pragma unroll
    for (int nt = 0; nt < 4; ++nt) {
      u16x4 pk;
      pk.x = f2b(s[mt][nt][0]);
      pk.y = f2b(s[mt][nt][1]);
      pk.z = f2b(s[mt][nt][2]);
      pk.w = f2b(s[mt][nt][3]);
      *(u16x4*)(&Pw[mt * 16 + l15][nt * 16 + quad * 4]) = pk;
    }

  // --- O' = (V^T P^T): o[mt][nt][reg]: d = nt*16+quad*4+reg, token = mt*16+l15 ---
  f32x4 o[2][4];
#pragma unroll
  for (int i = 0; i < 2; ++i)
#pragma unroll
    for (int j = 0; j < 4; ++j) o[i][j] = f32x4{0.f, 0.f, 0.f, 0.f};
  const long vbase = ((long)(b * 16 + h) * 64) * SEQ;
#pragma unroll
  for (int kt = 0; kt < 2; ++kt) {
    bf16x8 ap[2], bvf[4];
#pragma unroll
    for (int mt = 0; mt < 2; ++mt)
      ap[mt] = *(const bf16x8*)(&Pw[mt * 16 + l15][kt * 32 + quad * 8]);
#pragma unroll
    for (int nt = 0; nt < 4; ++nt)
      bvf[nt] = *(const bf16x8*)(vT + vbase + (long)(nt * 16 + l15) * SEQ + n * 64 + kt * 32 + quad * 8);
#pragma unroll
    for (int mt = 0; mt < 2; ++mt)
#pragma unroll
      for (int nt = 0; nt < 4; ++nt)
        o[mt][nt] = __builtin_amdgcn_mfma_f32_16x16x32_bf16(bvf[nt], ap[mt], o[mt][nt], 0, 0, 0);
  }

  // --- store attended bf16 [token][h*64+d], u16x4 ---
#pragma unroll
  for (int mt = 0; mt < 2; ++mt)
#pragma unroll
    for (int nt = 0; nt < 4; ++nt) {
      const long row = qrow0 + mt * 16 + l15;
      const long col = cbase + nt * 16 + quad * 4;
      u16x4 pk;
      pk.x = f2b(o[mt][nt][0]);
      pk.y = f2b(o[mt][nt][1]);
      pk.z = f2b(o[mt][nt][2]);
      pk.w = f2b(o[mt][nt][3]);
      *(u16x4*)(attended + row * HID + col) = pk;
    }

  // --- head-mean partial: sum this block's 4 heads -> Psum[block][32][64] ---
  __syncthreads();
  float* pbase = Psum + (long)idx * 2048;
  for (int i = tid; i < 32 * 64; i += 256) {
    const int r = i >> 6, c = i & 63;
    float sacc = 0.f;
#pragma unroll
    for (int w = 0; w < 4; ++w) sacc += b2f(Plds[w][r][c]);
    pbase[i] = sacc;
  }
}

// ---------------- fused O-projection GEMM + attn-map expand ----------------
__global__ __launch_bounds__(256, 2) void gemm_o_expand(
    const u16* __restrict__ A, const u16* __restrict__ Bw,
    const float* __restrict__ bias, float* __restrict__ Cout,
    const float* __restrict__ Psum, float* __restrict__ attn) {
  __shared__ __align__(16) u16 As[128 * 32];
  __shared__ __align__(16) u16 Bs[128 * 32];

  const int tid = threadIdx.x;

  if (blockIdx.x >= 512) {
    // ---- expand path: 2048 blocks x 4096 float4 each ----
    const long e = blockIdx.x - 512;
    const long f0 = e * 4096;
#pragma unroll
    for (int it = 0; it < 16; ++it) {
      const long f = f0 + it * 256 + tid;              // float4 index into attn
      const int b = (int)(f >> 22);                    // 2^22 float4 per batch
      const int rem = (int)(f & ((1 << 22) - 1));
      const int row = rem >> 10;                       // 1024 float4 per row
      const int c4 = rem & 1023;
      const int n = row >> 6;
      float4 val = {0.f, 0.f, 0.f, 0.f};
      const int d4 = c4 - n * 16;                      // diag cols = [n*64, n*64+64)
      if ((unsigned)d4 < 16u) {
        const int r = row & 63;
        const int half = r >> 5, rr = r & 31;
        const long base = ((long)((b * 64 + n) * 8 + half)) * 2048 + rr * 64 + d4 * 4;
        float4 p0 = *(const float4*)(Psum + base);
        float4 p1 = *(const float4*)(Psum + base + 4096);
        float4 p2 = *(const float4*)(Psum + base + 8192);
        float4 p3 = *(const float4*)(Psum + base + 12288);
        val.x = (p0.x + p1.x + p2.x + p3.x) * (1.f / 16.f);
        val.y = (p0.y + p1.y + p2.y + p3.y) * (1.f / 16.f);
        val.z = (p0.z + p1.z + p2.z + p3.z) * (1.f / 16.f);
        val.w = (p0.w + p1.w + p2.w + p3.w) * (1.f / 16.f);
      }
      ((float4*)attn)[f] = val;
    }
    return;
  }

  const long brow = (long)(blockIdx.x >> 3) * 128;
  const long bcol = (long)(blockIdx.x & 7) * 128;
  gemm_core<1>(A, Bw, bias, Cout, As, Bs, brow, bcol);
}

extern "C" void kernel_launch(void* const* d_in, const int* in_sizes, int n_in,
                              void* d_out, int out_size, void* d_ws, size_t ws_size,
                              hipStream_t stream) {
  (void)in_sizes; (void)n_in; (void)out_size; (void)ws_size;
  const float* query = (const float*)d_in[0];
  const float* key   = (const float*)d_in[1];
  const float* value = (const float*)d_in[2];
  const float* Wq = (const float*)d_in[3];
  const float* bq = (const float*)d_in[4];
  const float* Wk = (const float*)d_in[5];
  const float* bk = (const float*)d_in[6];
  const float* Wv = (const float*)d_in[7];
  const float* bv = (const float*)d_in[8];
  const float* Wo = (const float*)d_in[9];
  const float* bo = (const float*)d_in[10];

  float* out  = (float*)d_out;
  float* attn = out + (size_t)BATCH * SEQ * HID;   // +8388608 floats

  char* ws = (char*)d_ws;
  const size_t MB = (size_t)1 << 20;
  // Workspace map (NO overlaps — vT is 16 MB: 88..104):
  //   xq 0-16 | xk 16-32 | xv 32-48 | wq/wk/wv/wo 48-56 | qp 56-72 | kp 72-88
  //   vT 88-104 | Psum 104-112
  u16* xq = (u16*)(ws + 0 * MB);    // later reused as 'attended'
  u16* xk = (u16*)(ws + 16 * MB);
  u16* xv = (u16*)(ws + 32 * MB);
  u16* wq = (u16*)(ws + 48 * MB);
  u16* wk = (u16*)(ws + 50 * MB);
  u16* wv = (u16*)(ws + 52 * MB);
  u16* wo = (u16*)(ws + 54 * MB);
  u16* qp = (u16*)(ws + 56 * MB);
  u16* kp = (u16*)(ws + 72 * MB);
  u16* vT = (u16*)(ws + 88 * MB);        // 16 MB: spans 88..104
  float* Psum = (float*)(ws + 104 * MB); // 8 MB: 104..112
  u16* att = xq;   // dead after gemm3 completes (attn_win runs strictly after)

  cvt_all<<<3584, 256, 0, stream>>>(query, key, value, Wq, Wk, Wv, Wo,
                                    xq, xk, xv, wq, wk, wv, wo);

  Gemm3Args ga;
  ga.A[0] = xq; ga.W[0] = wq; ga.bias[0] = bq; ga.C[0] = qp; ga.mode[0] = 0;
  ga.A[1] = xk; ga.W[1] = wk; ga.bias[1] = bk; ga.C[1] = kp; ga.mode[1] = 0;
  ga.A[2] = xv; ga.W[2] = wv; ga.bias[2] = bv; ga.C[2] = vT; ga.mode[2] = 2;
  dim3 g3(HID / 128, (BATCH * SEQ) / 128, 3);  // (8, 64, 3)
  gemm_bt_fused<<<g3, 256, 0, stream>>>(ga);

  attn_win<<<BATCH * 64 * 4 * 2, 256, 0, stream>>>(qp, kp, vT, att, Psum);

  gemm_o_expand<<<512 + 2048, 256, 0, stream>>>(att, wo, bo, out, Psum, attn);
}